// Round 6
// baseline (18289.427 us; speedup 1.0000x reference)
//
#include <hip/hip_runtime.h>
#include <hip/hip_fp16.h>

#define S 31
#define D 14
#define H 50
#define NB 16384
#define NITER 48
#define LAMR 1e-4f

// ws float-index layout
#define WS_D2   0      // 48: global sum ||F-X||^2 per iter
#define WS_F2   64     // 48: global sum ||F||^2 per iter
#define WS_WHP  128    // 52x16 fp32 Wh (padded rows 50,51 = 0)
#define WS_BHX  960    // 64: bh+bx fp32 (h>=50 -> 0)
#define WS_BO   1024   // 16: bo fp32 (d>=14 -> 0)
#define WS_WX2  1040   // 52x8 half2: Wx rows packed (d pairs), rows 50,51 = 0
#define WS_WO2  1456   // 14x26 half2: Wo rows packed (h pairs), hh=25 = 0
#define WS_WF2  1824   // 32x8 half2: Wf per-s slices (row 31 = 0, dd=7 = 0)
#define WS_OUTK 4096   // 48*NB floats

typedef _Float16 f16x2 __attribute__((ext_vector_type(2)));

#if defined(__has_builtin) && __has_builtin(__builtin_amdgcn_rcpf)
#define FRCP(x) __builtin_amdgcn_rcpf(x)
#else
#define FRCP(x) (1.0f/(x))
#endif

#if defined(__has_builtin) && __has_builtin(__builtin_amdgcn_exp2f)
#define FEXP2(x) __builtin_amdgcn_exp2f(x)
#else
#define FEXP2(x) exp2f(x)
#endif

#define FDOT2(a,b,c) __builtin_amdgcn_fdot2((a),(b),(c),false)

__device__ __forceinline__ f16x2 pkrtz(float a, float b){
  auto r = __builtin_amdgcn_cvt_pkrtz(a, b);
  return __builtin_bit_cast(f16x2, r);
}
#define PKRTZ(a,b) pkrtz((a),(b))

__device__ __forceinline__ f16x2 pack_rn(float a, float b){
  __half2 h = __floats2half2_rn(a, b);
  return __builtin_bit_cast(f16x2, h);
}

__device__ __forceinline__ f16x2 shfl1(f16x2 v){
  float f = __builtin_bit_cast(float, v);
  f = __shfl_xor(f, 1);
  return __builtin_bit_cast(f16x2, f);
}

// triangular index, i<=j, 6x6
#define AIJ(i,j) ((i)*6 - ((i)*((i)+1))/2 + (j))

__device__ __forceinline__ float tfast(float x){
  // tanh(x) = 1 - 2/(exp2(x*2*log2e)+1)
  float e = FEXP2(x * 2.8853900817779268f);
  return 1.f - 2.f * FRCP(e + 1.f);
}

__global__ void prep_kernel(const float* __restrict__ Wh, const float* __restrict__ bh,
                            const float* __restrict__ Wx, const float* __restrict__ bx,
                            const float* __restrict__ Wo, const float* __restrict__ bo,
                            const float* __restrict__ Wf, float* __restrict__ ws){
  int t = threadIdx.x;                       // 1 block x 256
  for (int i=t;i<128;i+=256) ws[i]=0.f;      // zero norm accumulators
  for (int i=t;i<832;i+=256){                // Wh padded to 52 rows x16
    int h=i>>4, d=i&15;
    ws[WS_WHP+i] = (h<H && d<D)? Wh[h*D+d] : 0.f;
  }
  for (int i=t;i<64;i+=256) ws[WS_BHX+i] = (i<H)? bh[i]+bx[i] : 0.f;
  for (int i=t;i<16;i+=256) ws[WS_BO+i]  = (i<D)? bo[i] : 0.f;
  __half2* wx2 = (__half2*)(ws + WS_WX2);    // 52 rows x 8
  for (int i=t;i<416;i+=256){
    int h=i>>3, dd=i&7, d0=2*dd, d1=2*dd+1;
    float a=(h<H && d0<D)?Wx[h*D+d0]:0.f, b=(h<H && d1<D)?Wx[h*D+d1]:0.f;
    wx2[i] = __floats2half2_rn(a,b);
  }
  __half2* wo2 = (__half2*)(ws + WS_WO2);    // 14 x 26 (hh)
  for (int i=t;i<364;i+=256){
    int d=i/26, hh=i-26*d, h0=2*hh, h1=2*hh+1;
    float a=(hh<25)?Wo[d*H+h0]:0.f, b=(hh<25)?Wo[d*H+h1]:0.f;
    wo2[i] = __floats2half2_rn(a,b);
  }
  __half2* wf2 = (__half2*)(ws + WS_WF2);    // 32 x 8
  for (int i=t;i<256;i+=256){
    int s=i>>3, dd=i&7, d0=2*dd, d1=2*dd+1;
    float a=(s<S && d0<D)?Wf[s*D+d0]:0.f, b=(s<S && d1<D)?Wf[s*D+d1]:0.f;
    wf2[i] = __floats2half2_rn(a,b);
  }
}

// Pair-split f-eval: this lane computes its 13 h-pairs (hh = hf*13 + i) into
// all-14 partial sums (NO bias: added after exchange to avoid double count),
// pair-exchange sums the halves, then each lane produces tanh only for its
// OWN d-half (fo[0..3]; half1 fo[3] = 0 pad), adding its own-half bias.
#define FEVAL() do{ \
  float oacc_[14]; \
  _Pragma("unroll") for (int d_=0; d_<14; ++d_) oacc_[d_] = 0.f; \
  _Pragma("unroll") \
  for (int i_=0; i_<13; ++i_){ \
    f16x2 hx2_ = hxr2[i_]; \
    float a0_ = (float)hx2_[0], b0_ = (float)hx2_[1]; \
    _Pragma("unroll") for (int q_=0;q_<7;++q_){ \
      a0_ = FDOT2(xvh[q_], wxb[(2*i_)*8+q_],   a0_); \
      b0_ = FDOT2(xvh[q_], wxb[(2*i_+1)*8+q_], b0_); } \
    f16x2 th_ = PKRTZ(tfast(a0_), tfast(b0_)); \
    _Pragma("unroll") for (int d_=0; d_<14; ++d_) \
      oacc_[d_] = FDOT2(th_, wob[d_*26+i_], oacc_[d_]); \
  } \
  _Pragma("unroll") for (int d_=0; d_<14; ++d_) oacc_[d_] += __shfl_xor(oacc_[d_], 1); \
  _Pragma("unroll") for (int i_=0;i_<3;++i_){ \
    float u0_ = (hf ? oacc_[8+2*i_] : oacc_[2*i_])   + bopb[2*i_]; \
    float u1_ = (hf ? oacc_[9+2*i_] : oacc_[2*i_+1]) + bopb[2*i_+1]; \
    fo[i_] = PKRTZ(tfast(u0_), tfast(u1_)); } \
  { f16x2 t3_ = PKRTZ(tfast(oacc_[6]+bopb[6]), tfast(oacc_[7]+bopb[7])); \
    fo[3] = hf ? zzv : t3_; } \
}while(0)

#define ZERO_INACT() do{ \
  if (!act){ \
    _Pragma("unroll") for (int i_=0;i_<4;++i_){ fo[i_]=zzv; go[i_]=zzv; } \
  } \
}while(0)

// reassemble full 14-dim x vector (xvh[7]) from own-half xo[4] + pair exchange
#define XRECON() do{ \
  f16x2 rx0_=shfl1(xo[0]), rx1_=shfl1(xo[1]), rx2_=shfl1(xo[2]), rx3_=shfl1(xo[3]); \
  xvh[0] = hf ? rx0_ : xo[0]; \
  xvh[1] = hf ? rx1_ : xo[1]; \
  xvh[2] = hf ? rx2_ : xo[2]; \
  xvh[3] = hf ? rx3_ : xo[3]; \
  xvh[4] = hf ? xo[0] : rx0_; \
  xvh[5] = hf ? xo[1] : rx1_; \
  xvh[6] = hf ? xo[2] : rx2_; \
}while(0)

// Shift-based history push; all reductions over the FULL 64-lane wave
// (dims split across lane pairs, s across pair groups) in one batched butterfly.
#define PUSHB(DOPROJ) do{ \
  float rv_[8]; \
  _Pragma("unroll") for (int j_=0;j_<5;++j_){ \
    float acc_=0.f; \
    _Pragma("unroll") for (int i_=0;i_<4;++i_) acc_ = FDOT2(go[i_], Gh[(j_+1)*4+i_], acc_); \
    rv_[j_] = acc_; } \
  d2l=0.f; f2l=0.f; \
  _Pragma("unroll") for (int i_=0;i_<4;++i_){ \
    d2l = FDOT2(go[i_], go[i_], d2l); \
    f2l = FDOT2(fo[i_], fo[i_], f2l); } \
  rv_[5]=d2l; rv_[6]=f2l; rv_[7]=0.f; \
  if (DOPROJ){ \
    float pa_=0.f; \
    _Pragma("unroll") for (int i_=0;i_<4;++i_) pa_ = FDOT2(fo[i_], wfo[i_], pa_); \
    rv_[7]=pa_; } \
  _Pragma("unroll") for (int m_=1;m_<64;m_<<=1) \
    _Pragma("unroll") for (int i_=0;i_<8;++i_) rv_[i_] += __shfl_xor(rv_[i_], m_); \
  d2r = rv_[5]; f2r = rv_[6]; po_red = rv_[7]; \
  _Pragma("unroll") for (int j_=0;j_<5;++j_) \
    _Pragma("unroll") for (int i_=0;i_<4;++i_){ \
      Fh[j_*4+i_] = Fh[(j_+1)*4+i_]; Gh[j_*4+i_] = Gh[(j_+1)*4+i_]; } \
  _Pragma("unroll") for (int i_=0;i_<4;++i_){ Fh[20+i_]=fo[i_]; Gh[20+i_]=go[i_]; } \
  _Pragma("unroll") for (int i_=0;i_<5;++i_) \
    _Pragma("unroll") for (int j_=i_;j_<5;++j_) GG[AIJ(i_,j_)] = GG[AIJ(i_+1,j_+1)]; \
  _Pragma("unroll") for (int j_=0;j_<5;++j_) GG[AIJ(j_,5)] = rv_[j_]; \
  GG[AIJ(5,5)] = d2r; \
}while(0)

__global__ __launch_bounds__(256, 4)
void solver_kernel(const float* __restrict__ x,
                   const float* __restrict__ whp, const float* __restrict__ bhx,
                   const float* __restrict__ bop,
                   const f16x2* __restrict__ wx2, const f16x2* __restrict__ wo2,
                   const f16x2* __restrict__ wf2,
                   float* __restrict__ outk, float* __restrict__ d2p, float* __restrict__ f2p){
  const int tid  = threadIdx.x;
  const int lane = tid & 63;
  const int hf   = lane & 1;          // which half of dims/h this lane owns
  const int s    = lane >> 1;         // sequence position (0..31; 31 inactive)
  const int elem = blockIdx.x*4 + (tid>>6);   // one elem per 64-lane wave
  const bool act = (s < S);

  // per-lane hx slice: 13 f16x2, stride 13 dwords (odd -> bank spread)
  __shared__ f16x2 hx2_sh[256*13];    // 13312 B
  f16x2* hxw2 = hx2_sh + tid*13;

  // per-half weight bases (uniform within each half of the wave)
  const float* whb = whp + hf*416;    // 26 rows x 16
  const float* bhb = bhx + hf*26;
  const float* bopb = bop + hf*8;     // own-half output bias (14,15 = 0 pad)
  const f16x2* wxb = wx2 + hf*208;    // 26 rows x 8
  const f16x2* wob = wo2 + hf*13;     // within-row hh offset

  { // prologue: hx[h] = x_s . Wh_h + bh_h + bx_h for this lane's 13 h-pairs
    float xd[D];
#pragma unroll
    for (int d=0; d<D; ++d) xd[d]=0.f;
    if (act){
      const float* xr = x + ((size_t)elem*S + s)*D;
#pragma unroll
      for (int d=0; d<D; ++d) xd[d]=xr[d];
    }
#pragma unroll 4
    for (int i=0; i<13; ++i){
      float a0 = bhb[2*i], a1 = bhb[2*i+1];
#pragma unroll
      for (int d=0; d<D; ++d){
        a0 += xd[d]*whb[(2*i)*16+d];
        a1 += xd[d]*whb[(2*i+1)*16+d];
      }
      f16x2 hv = pack_rn(a0, a1);
      if (i==12) hv = hf ? f16x2{(_Float16)0.f,(_Float16)0.f} : hv;  // hh=25 pad
      hxw2[i] = hv;
    }
  }
  const f16x2* hxr2 = hxw2;
  const f16x2 zzv = {(_Float16)0.f, (_Float16)0.f};
  // per-lane Wf slice (own d-half of row s; half1 slot 3 is zero from prep)
  f16x2 wfo[4];
  {
    const f16x2* wfb = wf2 + s*8 + hf*4;
#pragma unroll
    for (int i=0;i<4;++i) wfo[i] = wfb[i];
  }

  f16x2 Fh[24], Gh[24], xvh[7], xo[4], fo[4], go[4];
  float GG[21];
  float d2l, f2l, d2r, f2r, po_red;
#pragma unroll
  for (int i=0;i<24;++i){ Fh[i]=zzv; Gh[i]=zzv; }
#pragma unroll
  for (int i=0;i<21;++i) GG[i]=0.f;

  // init entry 0: X0=0, F0=f(0)
#pragma unroll
  for (int q=0;q<7;++q) xvh[q]=zzv;
#pragma unroll
  for (int i=0;i<4;++i) xo[i]=zzv;
  FEVAL();
#pragma unroll
  for (int i=0;i<4;++i) go[i]=fo[i]-xo[i];
  ZERO_INACT();
  PUSHB(0);
  // init entry 1: X1=F0, F1=f(F0)
#pragma unroll
  for (int i=0;i<4;++i) xo[i]=fo[i];
  XRECON();
  FEVAL();
#pragma unroll
  for (int i=0;i<4;++i) go[i]=fo[i]-xo[i];
  ZERO_INACT();
  PUSHB(0);

#pragma unroll 1
  for (int kk=2; kk<50; ++kk){
    float A_[21], invd[6], yv[6];
    if (kk >= 6){
#pragma unroll
      for (int i=0;i<6;++i)
#pragma unroll
        for (int j=i;j<6;++j) A_[AIJ(i,j)] = GG[AIJ(i,j)] + ((i==j)?LAMR:0.f);
    } else {
      int lo = 6-kk;
#pragma unroll
      for (int i=0;i<6;++i)
#pragma unroll
        for (int j=i;j<6;++j){
          float v = GG[AIJ(i,j)] + ((i==j)?LAMR:0.f);
          A_[AIJ(i,j)] = (i>=lo)? v : ((i==j)?1e30f:0.f);
        }
    }
#pragma unroll
    for (int i=0;i<6;++i) yv[i]=1.f;
    // symmetric GE (no pivoting; SPD + big-diag pads)
#pragma unroll
    for (int p=0;p<6;++p){
      invd[p] = FRCP(A_[AIJ(p,p)]);
#pragma unroll
      for (int i=p+1;i<6;++i){
        float m = A_[AIJ(p,i)]*invd[p];
#pragma unroll
        for (int j=i;j<6;++j) A_[AIJ(i,j)] -= m*A_[AIJ(p,j)];
        yv[i] -= m*yv[p];
      }
    }
#pragma unroll
    for (int p=5;p>=0;--p){
      float acc=yv[p];
#pragma unroll
      for (int j=p+1;j<6;++j) acc -= A_[AIJ(p,j)]*yv[j];
      yv[p]=acc*invd[p];
    }
    float isum = FRCP(yv[0]+yv[1]+yv[2]+yv[3]+yv[4]+yv[5]);
    // Xk = sum_j alpha_j F_j  (own half; fp16 packed)
#pragma unroll
    for (int i=0;i<4;++i) xo[i]=zzv;
#pragma unroll
    for (int j=0;j<6;++j){
      _Float16 ah = (_Float16)(yv[j]*isum);
      f16x2 a2 = {ah, ah};
#pragma unroll
      for (int i=0;i<4;++i) xo[i] += a2*Fh[j*4+i];
    }
    XRECON();
    FEVAL();
#pragma unroll
    for (int i=0;i<4;++i) go[i]=fo[i]-xo[i];
    ZERO_INACT();
    PUSHB(1);
    if (lane==0){
      atomicAdd(&d2p[kk-2], d2r);
      atomicAdd(&f2p[kk-2], f2r);
      outk[(size_t)(kk-2)*NB + elem] = po_red;
    }
  }
}

__global__ void final_kernel(const float* __restrict__ d2p, const float* __restrict__ f2p,
                             const float* __restrict__ outk, const float* __restrict__ bf,
                             float* __restrict__ out){
  int b = blockIdx.x*blockDim.x + threadIdx.x;
  float best = 1e8f; int kst = 0;
  for (int k=0;k<NITER;++k){
    float rel = sqrtf(d2p[k]) / (1e-5f + sqrtf(f2p[k]));
    if (rel < best){ best = rel; kst = k; }
  }
  out[b] = outk[(size_t)kst*NB + b] + bf[0];
}

extern "C" void kernel_launch(void* const* d_in, const int* in_sizes, int n_in,
                              void* d_out, int out_size, void* d_ws, size_t ws_size,
                              hipStream_t stream){
  const float* x  = (const float*)d_in[0];
  const float* Wh = (const float*)d_in[1];
  const float* bh = (const float*)d_in[2];
  const float* Wx = (const float*)d_in[3];
  const float* bx = (const float*)d_in[4];
  const float* Wo = (const float*)d_in[5];
  const float* bo = (const float*)d_in[6];
  const float* Wf = (const float*)d_in[7];
  const float* bf = (const float*)d_in[8];
  float* ws  = (float*)d_ws;
  float* out = (float*)d_out;

  hipLaunchKernelGGL(prep_kernel, dim3(1), dim3(256), 0, stream, Wh,bh,Wx,bx,Wo,bo,Wf,ws);
  hipLaunchKernelGGL(solver_kernel, dim3(NB/4), dim3(256), 0, stream,
                     x, ws+WS_WHP, ws+WS_BHX, ws+WS_BO,
                     (const f16x2*)(ws+WS_WX2), (const f16x2*)(ws+WS_WO2), (const f16x2*)(ws+WS_WF2),
                     ws+WS_OUTK, ws+WS_D2, ws+WS_F2);
  hipLaunchKernelGGL(final_kernel, dim3(NB/256), dim3(256), 0, stream,
                     ws+WS_D2, ws+WS_F2, ws+WS_OUTK, bf, out);
}

// Round 7
// 14950.088 us; speedup vs baseline: 1.2234x; 1.2234x over previous
//
#include <hip/hip_runtime.h>
#include <hip/hip_fp16.h>

#define S 31
#define D 14
#define H 50
#define NB 16384
#define NITER 48
#define LAMR 1e-4f

// ws float-index layout
#define WS_D2   0      // 48: global sum ||F-X||^2 per iter
#define WS_F2   64     // 48: global sum ||F||^2 per iter
#define WS_WHP  128    // 52x16 fp32 Wh (padded rows 50,51 = 0)
#define WS_BHX  960    // 64: bh+bx fp32 (h>=50 -> 0)
#define WS_BO   1024   // 16: bo fp32 (d>=14 -> 0)
#define WS_WX2  1040   // 52x8 half2: Wx rows packed (d pairs), rows 50,51 = 0
#define WS_WO2  1456   // 14x26 half2: Wo rows packed (h pairs), hh=25 = 0
#define WS_WF2  1824   // 32x8 half2: Wf per-s slices (row 31 = 0, dd=7 = 0)
#define WS_OUTK 4096   // 48*NB floats

typedef _Float16 f16x2 __attribute__((ext_vector_type(2)));

#if defined(__has_builtin) && __has_builtin(__builtin_amdgcn_rcpf)
#define FRCP(x) __builtin_amdgcn_rcpf(x)
#else
#define FRCP(x) (1.0f/(x))
#endif

#if defined(__has_builtin) && __has_builtin(__builtin_amdgcn_exp2f)
#define FEXP2(x) __builtin_amdgcn_exp2f(x)
#else
#define FEXP2(x) exp2f(x)
#endif

#define FDOT2(a,b,c) __builtin_amdgcn_fdot2((a),(b),(c),false)

__device__ __forceinline__ f16x2 pkrtz(float a, float b){
  auto r = __builtin_amdgcn_cvt_pkrtz(a, b);
  return __builtin_bit_cast(f16x2, r);
}
#define PKRTZ(a,b) pkrtz((a),(b))

__device__ __forceinline__ f16x2 pack_rn(float a, float b){
  __half2 h = __floats2half2_rn(a, b);
  return __builtin_bit_cast(f16x2, h);
}

__device__ __forceinline__ f16x2 shfl1(f16x2 v){
  float f = __builtin_bit_cast(float, v);
  f = __shfl_xor(f, 1);
  return __builtin_bit_cast(f16x2, f);
}

// triangular index, i<=j, 6x6
#define AIJ(i,j) ((i)*6 - ((i)*((i)+1))/2 + (j))

__device__ __forceinline__ float tfast(float x){
  // tanh(x) = 1 - 2/(exp2(x*2*log2e)+1)
  float e = FEXP2(x * 2.8853900817779268f);
  return 1.f - 2.f * FRCP(e + 1.f);
}

__global__ void prep_kernel(const float* __restrict__ Wh, const float* __restrict__ bh,
                            const float* __restrict__ Wx, const float* __restrict__ bx,
                            const float* __restrict__ Wo, const float* __restrict__ bo,
                            const float* __restrict__ Wf, float* __restrict__ ws){
  int t = threadIdx.x;                       // 1 block x 256
  for (int i=t;i<128;i+=256) ws[i]=0.f;      // zero norm accumulators
  for (int i=t;i<832;i+=256){                // Wh padded to 52 rows x16
    int h=i>>4, d=i&15;
    ws[WS_WHP+i] = (h<H && d<D)? Wh[h*D+d] : 0.f;
  }
  for (int i=t;i<64;i+=256) ws[WS_BHX+i] = (i<H)? bh[i]+bx[i] : 0.f;
  for (int i=t;i<16;i+=256) ws[WS_BO+i]  = (i<D)? bo[i] : 0.f;
  __half2* wx2 = (__half2*)(ws + WS_WX2);    // 52 rows x 8
  for (int i=t;i<416;i+=256){
    int h=i>>3, dd=i&7, d0=2*dd, d1=2*dd+1;
    float a=(h<H && d0<D)?Wx[h*D+d0]:0.f, b=(h<H && d1<D)?Wx[h*D+d1]:0.f;
    wx2[i] = __floats2half2_rn(a,b);
  }
  __half2* wo2 = (__half2*)(ws + WS_WO2);    // 14 x 26 (hh)
  for (int i=t;i<364;i+=256){
    int d=i/26, hh=i-26*d, h0=2*hh, h1=2*hh+1;
    float a=(hh<25)?Wo[d*H+h0]:0.f, b=(hh<25)?Wo[d*H+h1]:0.f;
    wo2[i] = __floats2half2_rn(a,b);
  }
  __half2* wf2 = (__half2*)(ws + WS_WF2);    // 32 x 8
  for (int i=t;i<256;i+=256){
    int s=i>>3, dd=i&7, d0=2*dd, d1=2*dd+1;
    float a=(s<S && d0<D)?Wf[s*D+d0]:0.f, b=(s<S && d1<D)?Wf[s*D+d1]:0.f;
    wf2[i] = __floats2half2_rn(a,b);
  }
}

// Pair-split f-eval: this lane computes its 13 h-pairs (hh = hf*13 + i) into
// all-14 partial sums (NO bias here: added after exchange), pair-exchange
// sums halves, then each lane produces tanh only for its OWN d-half
// (fo[0..3]; half1 fo[3] = 0 pad), adding its own-half bias.
#define FEVAL() do{ \
  float oacc_[14]; \
  _Pragma("unroll") for (int d_=0; d_<14; ++d_) oacc_[d_] = 0.f; \
  _Pragma("unroll") \
  for (int i_=0; i_<13; ++i_){ \
    f16x2 hx2_ = hxr2[i_]; \
    float a0_ = (float)hx2_[0], b0_ = (float)hx2_[1]; \
    _Pragma("unroll") for (int q_=0;q_<7;++q_){ \
      a0_ = FDOT2(xvh[q_], wxb[(2*i_)*8+q_],   a0_); \
      b0_ = FDOT2(xvh[q_], wxb[(2*i_+1)*8+q_], b0_); } \
    f16x2 th_ = PKRTZ(tfast(a0_), tfast(b0_)); \
    _Pragma("unroll") for (int d_=0; d_<14; ++d_) \
      oacc_[d_] = FDOT2(th_, wob[d_*26+i_], oacc_[d_]); \
  } \
  _Pragma("unroll") for (int d_=0; d_<14; ++d_) oacc_[d_] += __shfl_xor(oacc_[d_], 1); \
  _Pragma("unroll") for (int i_=0;i_<3;++i_){ \
    float u0_ = (hf ? oacc_[8+2*i_] : oacc_[2*i_])   + bopb[2*i_]; \
    float u1_ = (hf ? oacc_[9+2*i_] : oacc_[2*i_+1]) + bopb[2*i_+1]; \
    fo[i_] = PKRTZ(tfast(u0_), tfast(u1_)); } \
  { f16x2 t3_ = PKRTZ(tfast(oacc_[6]+bopb[6]), tfast(oacc_[7]+bopb[7])); \
    fo[3] = hf ? zzv : t3_; } \
}while(0)

// go = fo - ownhalf(xvh): xvh own-half slots hold this lane's X exactly
// (set by XRECON / zeroed at init), so no separate xo array is kept live.
#define MAKE_GO() do{ \
  _Pragma("unroll") for (int i_=0;i_<4;++i_){ \
    f16x2 xoi_ = hf ? ((i_<3) ? xvh[4+i_] : zzv) : xvh[i_]; \
    go[i_] = fo[i_] - xoi_; } \
}while(0)

#define ZERO_INACT() do{ \
  if (!act){ \
    _Pragma("unroll") for (int i_=0;i_<4;++i_){ fo[i_]=zzv; go[i_]=zzv; } \
  } \
}while(0)

// reassemble full 14-dim x vector (xvh[7]) from own-half xt[4] + pair exchange
#define XRECON() do{ \
  f16x2 rx0_=shfl1(xt[0]), rx1_=shfl1(xt[1]), rx2_=shfl1(xt[2]), rx3_=shfl1(xt[3]); \
  xvh[0] = hf ? rx0_ : xt[0]; \
  xvh[1] = hf ? rx1_ : xt[1]; \
  xvh[2] = hf ? rx2_ : xt[2]; \
  xvh[3] = hf ? rx3_ : xt[3]; \
  xvh[4] = hf ? xt[0] : rx0_; \
  xvh[5] = hf ? xt[1] : rx1_; \
  xvh[6] = hf ? xt[2] : rx2_; \
}while(0)

// Shift-based history push; all reductions over the FULL 64-lane wave
// (dims split across lane pairs, s across pair groups) in one batched butterfly.
#define PUSHB(DOPROJ) do{ \
  float rv_[8]; \
  _Pragma("unroll") for (int j_=0;j_<5;++j_){ \
    float acc_=0.f; \
    _Pragma("unroll") for (int i_=0;i_<4;++i_) acc_ = FDOT2(go[i_], Gh[(j_+1)*4+i_], acc_); \
    rv_[j_] = acc_; } \
  d2l=0.f; f2l=0.f; \
  _Pragma("unroll") for (int i_=0;i_<4;++i_){ \
    d2l = FDOT2(go[i_], go[i_], d2l); \
    f2l = FDOT2(fo[i_], fo[i_], f2l); } \
  rv_[5]=d2l; rv_[6]=f2l; rv_[7]=0.f; \
  if (DOPROJ){ \
    float pa_=0.f; \
    _Pragma("unroll") for (int i_=0;i_<4;++i_) pa_ = FDOT2(fo[i_], wfo[i_], pa_); \
    rv_[7]=pa_; } \
  _Pragma("unroll") for (int m_=1;m_<64;m_<<=1) \
    _Pragma("unroll") for (int i_=0;i_<8;++i_) rv_[i_] += __shfl_xor(rv_[i_], m_); \
  d2r = rv_[5]; f2r = rv_[6]; po_red = rv_[7]; \
  _Pragma("unroll") for (int j_=0;j_<5;++j_) \
    _Pragma("unroll") for (int i_=0;i_<4;++i_){ \
      Fh[j_*4+i_] = Fh[(j_+1)*4+i_]; Gh[j_*4+i_] = Gh[(j_+1)*4+i_]; } \
  _Pragma("unroll") for (int i_=0;i_<4;++i_){ Fh[20+i_]=fo[i_]; Gh[20+i_]=go[i_]; } \
  _Pragma("unroll") for (int i_=0;i_<5;++i_) \
    _Pragma("unroll") for (int j_=i_;j_<5;++j_) GG[AIJ(i_,j_)] = GG[AIJ(i_+1,j_+1)]; \
  _Pragma("unroll") for (int j_=0;j_<5;++j_) GG[AIJ(j_,5)] = rv_[j_]; \
  GG[AIJ(5,5)] = d2r; \
}while(0)

__global__ __launch_bounds__(256, 3)
void solver_kernel(const float* __restrict__ x,
                   const float* __restrict__ whp, const float* __restrict__ bhx,
                   const float* __restrict__ bop,
                   const f16x2* __restrict__ wx2, const f16x2* __restrict__ wo2,
                   const f16x2* __restrict__ wf2,
                   float* __restrict__ outk, float* __restrict__ d2p, float* __restrict__ f2p){
  const int tid  = threadIdx.x;
  const int lane = tid & 63;
  const int hf   = lane & 1;          // which half of dims/h this lane owns
  const int s    = lane >> 1;         // sequence position (0..31; 31 inactive)
  const int elem = blockIdx.x*4 + (tid>>6);   // one elem per 64-lane wave
  const bool act = (s < S);

  // per-lane hx slice: 13 f16x2, stride 13 dwords (odd -> bank spread)
  __shared__ f16x2 hx2_sh[256*13];    // 13312 B
  f16x2* hxw2 = hx2_sh + tid*13;

  // per-half weight bases (uniform within each half of the wave)
  const float* whb = whp + hf*416;    // 26 rows x 16
  const float* bhb = bhx + hf*26;
  const float* bopb = bop + hf*8;     // own-half output bias (14,15 = 0 pad)
  const f16x2* wxb = wx2 + hf*208;    // 26 rows x 8
  const f16x2* wob = wo2 + hf*13;     // within-row hh offset

  { // prologue: hx[h] = x_s . Wh_h + bh_h + bx_h for this lane's 13 h-pairs
    float xd[D];
#pragma unroll
    for (int d=0; d<D; ++d) xd[d]=0.f;
    if (act){
      const float* xr = x + ((size_t)elem*S + s)*D;
#pragma unroll
      for (int d=0; d<D; ++d) xd[d]=xr[d];
    }
#pragma unroll 4
    for (int i=0; i<13; ++i){
      float a0 = bhb[2*i], a1 = bhb[2*i+1];
#pragma unroll
      for (int d=0; d<D; ++d){
        a0 += xd[d]*whb[(2*i)*16+d];
        a1 += xd[d]*whb[(2*i+1)*16+d];
      }
      f16x2 hv = pack_rn(a0, a1);
      if (i==12) hv = hf ? f16x2{(_Float16)0.f,(_Float16)0.f} : hv;  // hh=25 pad
      hxw2[i] = hv;
    }
  }
  const f16x2* hxr2 = hxw2;
  const f16x2 zzv = {(_Float16)0.f, (_Float16)0.f};
  // per-lane Wf slice (own d-half of row s; half1 slot 3 is zero from prep)
  f16x2 wfo[4];
  {
    const f16x2* wfb = wf2 + s*8 + hf*4;
#pragma unroll
    for (int i=0;i<4;++i) wfo[i] = wfb[i];
  }

  f16x2 Fh[24], Gh[24], xvh[7], fo[4], go[4];
  float GG[21];
  float d2l, f2l, d2r, f2r, po_red;
#pragma unroll
  for (int i=0;i<24;++i){ Fh[i]=zzv; Gh[i]=zzv; }
#pragma unroll
  for (int i=0;i<21;++i) GG[i]=0.f;

  // init entry 0: X0=0, F0=f(0)
#pragma unroll
  for (int q=0;q<7;++q) xvh[q]=zzv;
  FEVAL();
  MAKE_GO();
  ZERO_INACT();
  PUSHB(0);
  // init entry 1: X1=F0, F1=f(F0)
  {
    f16x2 xt[4];
#pragma unroll
    for (int i=0;i<4;++i) xt[i]=fo[i];
    XRECON();
  }
  FEVAL();
  MAKE_GO();
  ZERO_INACT();
  PUSHB(0);

#pragma unroll 1
  for (int kk=2; kk<50; ++kk){
    float A_[21], yv[6];
    if (kk >= 6){
#pragma unroll
      for (int i=0;i<6;++i)
#pragma unroll
        for (int j=i;j<6;++j) A_[AIJ(i,j)] = GG[AIJ(i,j)] + ((i==j)?LAMR:0.f);
    } else {
      int lo = 6-kk;
#pragma unroll
      for (int i=0;i<6;++i)
#pragma unroll
        for (int j=i;j<6;++j){
          float v = GG[AIJ(i,j)] + ((i==j)?LAMR:0.f);
          A_[AIJ(i,j)] = (i>=lo)? v : ((i==j)?1e30f:0.f);
        }
    }
#pragma unroll
    for (int i=0;i<6;++i) yv[i]=1.f;
    // symmetric GE (no pivoting; SPD + big-diag pads); diag holds reciprocal
#pragma unroll
    for (int p=0;p<6;++p){
      float ip = FRCP(A_[AIJ(p,p)]);
      A_[AIJ(p,p)] = ip;
#pragma unroll
      for (int i=p+1;i<6;++i){
        float m = A_[AIJ(p,i)]*ip;
#pragma unroll
        for (int j=i;j<6;++j) A_[AIJ(i,j)] -= m*A_[AIJ(p,j)];
        yv[i] -= m*yv[p];
      }
    }
#pragma unroll
    for (int p=5;p>=0;--p){
      float acc=yv[p];
#pragma unroll
      for (int j=p+1;j<6;++j) acc -= A_[AIJ(p,j)]*yv[j];
      yv[p]=acc*A_[AIJ(p,p)];
    }
    float isum = FRCP(yv[0]+yv[1]+yv[2]+yv[3]+yv[4]+yv[5]);
    // Xk = sum_j alpha_j F_j  (own half; fp16 packed; xt dies at XRECON)
    {
      f16x2 xt[4];
#pragma unroll
      for (int i=0;i<4;++i) xt[i]=zzv;
#pragma unroll
      for (int j=0;j<6;++j){
        _Float16 ah = (_Float16)(yv[j]*isum);
        f16x2 a2 = {ah, ah};
#pragma unroll
        for (int i=0;i<4;++i) xt[i] += a2*Fh[j*4+i];
      }
      XRECON();
    }
    FEVAL();
    MAKE_GO();
    ZERO_INACT();
    PUSHB(1);
    if (lane==0){
      atomicAdd(&d2p[kk-2], d2r);
      atomicAdd(&f2p[kk-2], f2r);
      outk[(size_t)(kk-2)*NB + elem] = po_red;
    }
  }
}

__global__ void final_kernel(const float* __restrict__ d2p, const float* __restrict__ f2p,
                             const float* __restrict__ outk, const float* __restrict__ bf,
                             float* __restrict__ out){
  int b = blockIdx.x*blockDim.x + threadIdx.x;
  float best = 1e8f; int kst = 0;
  for (int k=0;k<NITER;++k){
    float rel = sqrtf(d2p[k]) / (1e-5f + sqrtf(f2p[k]));
    if (rel < best){ best = rel; kst = k; }
  }
  out[b] = outk[(size_t)kst*NB + b] + bf[0];
}

extern "C" void kernel_launch(void* const* d_in, const int* in_sizes, int n_in,
                              void* d_out, int out_size, void* d_ws, size_t ws_size,
                              hipStream_t stream){
  const float* x  = (const float*)d_in[0];
  const float* Wh = (const float*)d_in[1];
  const float* bh = (const float*)d_in[2];
  const float* Wx = (const float*)d_in[3];
  const float* bx = (const float*)d_in[4];
  const float* Wo = (const float*)d_in[5];
  const float* bo = (const float*)d_in[6];
  const float* Wf = (const float*)d_in[7];
  const float* bf = (const float*)d_in[8];
  float* ws  = (float*)d_ws;
  float* out = (float*)d_out;

  hipLaunchKernelGGL(prep_kernel, dim3(1), dim3(256), 0, stream, Wh,bh,Wx,bx,Wo,bo,Wf,ws);
  hipLaunchKernelGGL(solver_kernel, dim3(NB/4), dim3(256), 0, stream,
                     x, ws+WS_WHP, ws+WS_BHX, ws+WS_BO,
                     (const f16x2*)(ws+WS_WX2), (const f16x2*)(ws+WS_WO2), (const f16x2*)(ws+WS_WF2),
                     ws+WS_OUTK, ws+WS_D2, ws+WS_F2);
  hipLaunchKernelGGL(final_kernel, dim3(NB/256), dim3(256), 0, stream,
                     ws+WS_D2, ws+WS_F2, ws+WS_OUTK, bf, out);
}

// Round 8
// 2890.776 us; speedup vs baseline: 6.3268x; 5.1717x over previous
//
#include <hip/hip_runtime.h>
#include <hip/hip_fp16.h>

#define S 31
#define D 14
#define H 50
#define NB 16384
#define NITER 48
#define LAMR 1e-4f

// ws float-index layout
#define WS_D2   0      // 48: global sum ||F-X||^2 per iter
#define WS_F2   64     // 48: global sum ||F||^2 per iter
#define WS_WHP  128    // 50x16 fp32 Wh (padded)
#define WS_BHX  928    // 64: bh+bx fp32
#define WS_BO   992    // 16: bo fp32
#define WS_WX2  1024   // 50x8 half2: Wx rows packed (d pairs)
#define WS_WO2  1424   // 14x26 half2: Wo rows packed (h pairs)
#define WS_WF2  1792   // 32x8 half2: Wf per-s slices (row 31 = 0)
#define WS_OUTK 4096   // 48*NB floats

typedef _Float16 f16x2 __attribute__((ext_vector_type(2)));

#if defined(__has_builtin) && __has_builtin(__builtin_amdgcn_rcpf)
#define FRCP(x) __builtin_amdgcn_rcpf(x)
#else
#define FRCP(x) (1.0f/(x))
#endif

#if defined(__has_builtin) && __has_builtin(__builtin_amdgcn_exp2f)
#define FEXP2(x) __builtin_amdgcn_exp2f(x)
#else
#define FEXP2(x) exp2f(x)
#endif

#define FDOT2(a,b,c) __builtin_amdgcn_fdot2((a),(b),(c),false)

__device__ __forceinline__ f16x2 pkrtz(float a, float b){
  auto r = __builtin_amdgcn_cvt_pkrtz(a, b);
  return __builtin_bit_cast(f16x2, r);
}
#define PKRTZ(a,b) pkrtz((a),(b))

__device__ __forceinline__ f16x2 pack_rn(float a, float b){
  __half2 h = __floats2half2_rn(a, b);
  return __builtin_bit_cast(f16x2, h);
}

// triangular index, i<=j, 6x6
#define AIJ(i,j) ((i)*6 - ((i)*((i)+1))/2 + (j))

__device__ __forceinline__ float tfast(float x){
  // tanh(x) = 1 - 2/(exp2(x*2*log2e)+1)
  float e = FEXP2(x * 2.8853900817779268f);
  return 1.f - 2.f * FRCP(e + 1.f);
}

__global__ void prep_kernel(const float* __restrict__ Wh, const float* __restrict__ bh,
                            const float* __restrict__ Wx, const float* __restrict__ bx,
                            const float* __restrict__ Wo, const float* __restrict__ bo,
                            const float* __restrict__ Wf, float* __restrict__ ws){
  int t = threadIdx.x;                       // 1 block x 256
  for (int i=t;i<128;i+=256) ws[i]=0.f;      // zero norm accumulators
  for (int i=t;i<800;i+=256){
    int h=i>>4, d=i&15;
    ws[WS_WHP+i] = (d<D)? Wh[h*D+d] : 0.f;
  }
  for (int i=t;i<64;i+=256) ws[WS_BHX+i] = (i<H)? bh[i]+bx[i] : 0.f;
  for (int i=t;i<16;i+=256) ws[WS_BO+i]  = (i<D)? bo[i] : 0.f;
  __half2* wx2 = (__half2*)(ws + WS_WX2);
  for (int i=t;i<400;i+=256){
    int h=i>>3, dd=i&7, d0=2*dd, d1=2*dd+1;
    float a=(d0<D)?Wx[h*D+d0]:0.f, b=(d1<D)?Wx[h*D+d1]:0.f;
    wx2[i] = __floats2half2_rn(a,b);
  }
  __half2* wo2 = (__half2*)(ws + WS_WO2);
  for (int i=t;i<364;i+=256){
    int d=i/26, hh=i-26*d, h0=2*hh, h1=2*hh+1;
    float a=(hh<25)?Wo[d*H+h0]:0.f, b=(hh<25)?Wo[d*H+h1]:0.f;
    wo2[i] = __floats2half2_rn(a,b);
  }
  __half2* wf2 = (__half2*)(ws + WS_WF2);
  for (int i=t;i<256;i+=256){
    int s=i>>3, dd=i&7, d0=2*dd, d1=2*dd+1;
    float a=(s<S && d0<D)?Wf[s*D+d0]:0.f, b=(s<S && d1<D)?Wf[s*D+d1]:0.f;
    wf2[i] = __floats2half2_rn(a,b);
  }
}

// f-eval, fused layers; weights via wave-uniform addresses (s_load/SGPR path).
#define FEVAL() do{ \
  float oacc_[14]; \
  _Pragma("unroll") for (int d_=0; d_<14; ++d_) oacc_[d_] = bop[d_]; \
  _Pragma("unroll") \
  for (int hh_=0; hh_<25; ++hh_){ \
    f16x2 hx2_ = hxr2[hh_]; \
    float a0_ = (float)hx2_[0], b0_ = (float)hx2_[1]; \
    _Pragma("unroll") for (int q_=0;q_<7;++q_){ \
      a0_ = FDOT2(xvh[q_], wx2[(2*hh_)*8+q_],   a0_); \
      b0_ = FDOT2(xvh[q_], wx2[(2*hh_+1)*8+q_], b0_); } \
    f16x2 th_ = PKRTZ(tfast(a0_), tfast(b0_)); \
    _Pragma("unroll") for (int d_=0; d_<14; ++d_) \
      oacc_[d_] = FDOT2(th_, wo2[d_*26+hh_], oacc_[d_]); \
  } \
  _Pragma("unroll") for (int dp_=0; dp_<7; ++dp_) \
    fvh[dp_] = PKRTZ(tfast(oacc_[2*dp_]), tfast(oacc_[2*dp_+1])); \
}while(0)

#define ZERO_INACT() do{ \
  if (!act){ \
    _Pragma("unroll") for (int q_=0;q_<7;++q_){ fvh[q_]=zzv; gvh[q_]=zzv; } \
  } \
}while(0)

// Shift-based history push (constant indices -> stays in regs).
// All 8 per-iteration 32-lane reductions batched into ONE interleaved butterfly.
#define PUSHB(DOPROJ) do{ \
  float rv_[8]; \
  _Pragma("unroll") for (int j_=0;j_<5;++j_){ \
    float acc_=0.f; \
    _Pragma("unroll") for (int q_=0;q_<7;++q_) acc_ = FDOT2(gvh[q_], Gh[(j_+1)*7+q_], acc_); \
    rv_[j_] = acc_; } \
  d2l=0.f; f2l=0.f; \
  _Pragma("unroll") for (int q_=0;q_<7;++q_){ \
    d2l = FDOT2(gvh[q_], gvh[q_], d2l); \
    f2l = FDOT2(fvh[q_], fvh[q_], f2l); } \
  rv_[5]=d2l; rv_[6]=f2l; rv_[7]=0.f; \
  if (DOPROJ){ \
    float pa_=0.f; \
    _Pragma("unroll") for (int q_=0;q_<7;++q_) pa_ = FDOT2(fvh[q_], wfr[q_], pa_); \
    rv_[7]=pa_; } \
  _Pragma("unroll") for (int m_=1;m_<32;m_<<=1) \
    _Pragma("unroll") for (int i_=0;i_<8;++i_) rv_[i_] += __shfl_xor(rv_[i_], m_); \
  d2r = rv_[5]; f2r = rv_[6]; po_red = rv_[7]; \
  _Pragma("unroll") for (int j_=0;j_<5;++j_) \
    _Pragma("unroll") for (int q_=0;q_<7;++q_){ \
      Fh[j_*7+q_] = Fh[(j_+1)*7+q_]; Gh[j_*7+q_] = Gh[(j_+1)*7+q_]; } \
  _Pragma("unroll") for (int q_=0;q_<7;++q_){ Fh[35+q_]=fvh[q_]; Gh[35+q_]=gvh[q_]; } \
  _Pragma("unroll") for (int i_=0;i_<5;++i_) \
    _Pragma("unroll") for (int j_=i_;j_<5;++j_) GG[AIJ(i_,j_)] = GG[AIJ(i_+1,j_+1)]; \
  _Pragma("unroll") for (int j_=0;j_<5;++j_) GG[AIJ(j_,5)] = rv_[j_]; \
  GG[AIJ(5,5)] = d2r; \
}while(0)

// One wave per block: finer scheduling granularity, smaller tail; no barriers.
__global__ __launch_bounds__(64, 3)
void solver_kernel(const float* __restrict__ x,
                   const float* __restrict__ whp, const float* __restrict__ bhx,
                   const float* __restrict__ bop,
                   const f16x2* __restrict__ wx2, const f16x2* __restrict__ wo2,
                   const f16x2* __restrict__ wf2,
                   float* __restrict__ outk, float* __restrict__ d2p, float* __restrict__ f2p){
  const int tid  = threadIdx.x;
  const int lane = tid & 63;
  const int s    = tid & 31;
  const int elem = blockIdx.x*2 + (tid>>5);
  const bool act = (s < S);

  // hx as f16x2, stride 27 words (odd -> all-bank spread)
  __shared__ f16x2 hx2_sh[64*27];           // 6912 B
  f16x2* hxw2 = hx2_sh + tid*27;

  { // prologue: hx[h] = x_s . Wh_h + bh_h + bx_h  (fp32, one RNE round to fp16)
    float xd[D];
#pragma unroll
    for (int d=0; d<D; ++d) xd[d]=0.f;
    if (act){
      const float* xr = x + ((size_t)elem*S + s)*D;
#pragma unroll
      for (int d=0; d<D; ++d) xd[d]=xr[d];
    }
#pragma unroll 5
    for (int hp=0; hp<25; ++hp){
      float a0 = bhx[2*hp], a1 = bhx[2*hp+1];
#pragma unroll
      for (int d=0; d<D; ++d){
        a0 += xd[d]*whp[(2*hp)*16+d];
        a1 += xd[d]*whp[(2*hp+1)*16+d];
      }
      hxw2[hp] = pack_rn(a0, a1);
    }
  }
  const f16x2* hxr2 = hxw2;
  const f16x2 zzv = {(_Float16)0.f, (_Float16)0.f};
  const f16x2* wfr = wf2 + s*8;

  f16x2 Fh[42], Gh[42], xvh[7], fvh[7], gvh[7];
  float GG[21];
  float d2l, f2l, d2r, f2r, po_red;
#pragma unroll
  for (int i=0;i<42;++i){ Fh[i]=zzv; Gh[i]=zzv; }
#pragma unroll
  for (int i=0;i<21;++i) GG[i]=0.f;

  // init entry 0: X0=0, F0=f(0)
#pragma unroll
  for (int q=0;q<7;++q) xvh[q]=zzv;
  FEVAL();
#pragma unroll
  for (int q=0;q<7;++q) gvh[q]=fvh[q]-xvh[q];
  ZERO_INACT();
  PUSHB(0);
  // init entry 1: X1=F0, F1=f(F0)
#pragma unroll
  for (int q=0;q<7;++q) xvh[q]=fvh[q];
  FEVAL();
#pragma unroll
  for (int q=0;q<7;++q) gvh[q]=fvh[q]-xvh[q];
  ZERO_INACT();
  PUSHB(0);

#pragma unroll 1
  for (int kk=2; kk<50; ++kk){
    float A_[21], invd[6], yv[6];
    if (kk >= 6){
#pragma unroll
      for (int i=0;i<6;++i)
#pragma unroll
        for (int j=i;j<6;++j) A_[AIJ(i,j)] = GG[AIJ(i,j)] + ((i==j)?LAMR:0.f);
    } else {
      int lo = 6-kk;
#pragma unroll
      for (int i=0;i<6;++i)
#pragma unroll
        for (int j=i;j<6;++j){
          float v = GG[AIJ(i,j)] + ((i==j)?LAMR:0.f);
          A_[AIJ(i,j)] = (i>=lo)? v : ((i==j)?1e30f:0.f);
        }
    }
#pragma unroll
    for (int i=0;i<6;++i) yv[i]=1.f;
    // symmetric GE (no pivoting; SPD + big-diag pads)
#pragma unroll
    for (int p=0;p<6;++p){
      invd[p] = FRCP(A_[AIJ(p,p)]);
#pragma unroll
      for (int i=p+1;i<6;++i){
        float m = A_[AIJ(p,i)]*invd[p];
#pragma unroll
        for (int j=i;j<6;++j) A_[AIJ(i,j)] -= m*A_[AIJ(p,j)];
        yv[i] -= m*yv[p];
      }
    }
#pragma unroll
    for (int p=5;p>=0;--p){
      float acc=yv[p];
#pragma unroll
      for (int j=p+1;j<6;++j) acc -= A_[AIJ(p,j)]*yv[j];
      yv[p]=acc*invd[p];
    }
    float isum = FRCP(yv[0]+yv[1]+yv[2]+yv[3]+yv[4]+yv[5]);
    // Xk = sum_j alpha_j F_j  (fp16 packed)
#pragma unroll
    for (int q=0;q<7;++q) xvh[q]=zzv;
#pragma unroll
    for (int j=0;j<6;++j){
      _Float16 ah = (_Float16)(yv[j]*isum);
      f16x2 a2 = {ah, ah};
#pragma unroll
      for (int q=0;q<7;++q) xvh[q] += a2*Fh[j*7+q];
    }
    FEVAL();
#pragma unroll
    for (int q=0;q<7;++q) gvh[q]=fvh[q]-xvh[q];
    ZERO_INACT();
    PUSHB(1);
    float d2w = d2r + __shfl_xor(d2r, 32);
    float f2w = f2r + __shfl_xor(f2r, 32);
    if (lane==0){ atomicAdd(&d2p[kk-2], d2w); atomicAdd(&f2p[kk-2], f2w); }
    if (s==0) outk[(size_t)(kk-2)*NB + elem] = po_red;
  }
}

__global__ void final_kernel(const float* __restrict__ d2p, const float* __restrict__ f2p,
                             const float* __restrict__ outk, const float* __restrict__ bf,
                             float* __restrict__ out){
  int b = blockIdx.x*blockDim.x + threadIdx.x;
  float best = 1e8f; int kst = 0;
  for (int k=0;k<NITER;++k){
    float rel = sqrtf(d2p[k]) / (1e-5f + sqrtf(f2p[k]));
    if (rel < best){ best = rel; kst = k; }
  }
  out[b] = outk[(size_t)kst*NB + b] + bf[0];
}

extern "C" void kernel_launch(void* const* d_in, const int* in_sizes, int n_in,
                              void* d_out, int out_size, void* d_ws, size_t ws_size,
                              hipStream_t stream){
  const float* x  = (const float*)d_in[0];
  const float* Wh = (const float*)d_in[1];
  const float* bh = (const float*)d_in[2];
  const float* Wx = (const float*)d_in[3];
  const float* bx = (const float*)d_in[4];
  const float* Wo = (const float*)d_in[5];
  const float* bo = (const float*)d_in[6];
  const float* Wf = (const float*)d_in[7];
  const float* bf = (const float*)d_in[8];
  float* ws  = (float*)d_ws;
  float* out = (float*)d_out;

  hipLaunchKernelGGL(prep_kernel, dim3(1), dim3(256), 0, stream, Wh,bh,Wx,bx,Wo,bo,Wf,ws);
  hipLaunchKernelGGL(solver_kernel, dim3(NB/2), dim3(64), 0, stream,
                     x, ws+WS_WHP, ws+WS_BHX, ws+WS_BO,
                     (const f16x2*)(ws+WS_WX2), (const f16x2*)(ws+WS_WO2), (const f16x2*)(ws+WS_WF2),
                     ws+WS_OUTK, ws+WS_D2, ws+WS_F2);
  hipLaunchKernelGGL(final_kernel, dim3(NB/256), dim3(256), 0, stream,
                     ws+WS_D2, ws+WS_F2, ws+WS_OUTK, bf, out);
}

// Round 9
// 2800.432 us; speedup vs baseline: 6.5309x; 1.0323x over previous
//
#include <hip/hip_runtime.h>
#include <hip/hip_fp16.h>

#define S 31
#define D 14
#define H 50
#define NB 16384
#define NITER 48
#define LAMR 1e-4f
#define TSC 2.8853900817779268f   // 2*log2(e), folded into weights at prep

// ws float-index layout
#define WS_D2   0      // 48: global sum ||F-X||^2 per iter
#define WS_F2   64     // 48: global sum ||F||^2 per iter
#define WS_WHP  128    // 50x16 fp32 Wh (padded, pre-scaled by TSC)
#define WS_BHX  928    // 64: (bh+bx)*TSC fp32
#define WS_BO   992    // 16: bo*TSC fp32
#define WS_WX2  1024   // 50x8 half2: Wx*TSC rows packed (d pairs)
#define WS_WO2  1424   // 14x26 half2: Wo*TSC rows packed (h pairs)
#define WS_WF2  1792   // 32x8 half2: Wf per-s slices (row 31 = 0), UNscaled
#define WS_OUTK 4096   // 48*NB floats

typedef _Float16 f16x2 __attribute__((ext_vector_type(2)));

#if defined(__has_builtin) && __has_builtin(__builtin_amdgcn_rcpf)
#define FRCP(x) __builtin_amdgcn_rcpf(x)
#else
#define FRCP(x) (1.0f/(x))
#endif

#if defined(__has_builtin) && __has_builtin(__builtin_amdgcn_exp2f)
#define FEXP2(x) __builtin_amdgcn_exp2f(x)
#else
#define FEXP2(x) exp2f(x)
#endif

#define FDOT2(a,b,c) __builtin_amdgcn_fdot2((a),(b),(c),false)

__device__ __forceinline__ f16x2 pkrtz(float a, float b){
  auto r = __builtin_amdgcn_cvt_pkrtz(a, b);
  return __builtin_bit_cast(f16x2, r);
}
#define PKRTZ(a,b) pkrtz((a),(b))

__device__ __forceinline__ f16x2 pack_rn(float a, float b){
  __half2 h = __floats2half2_rn(a, b);
  return __builtin_bit_cast(f16x2, h);
}

// DPP rotate-add within 16-lane rows: full-rate VALU, no LDS-pipe latency.
template<int CTRL>
__device__ __forceinline__ float dppadd(float v){
  int pv = __builtin_amdgcn_update_dpp(0, __builtin_bit_cast(int, v),
                                       CTRL, 0xF, 0xF, true);
  return v + __builtin_bit_cast(float, pv);
}

// triangular index, i<=j, 6x6
#define AIJ(i,j) ((i)*6 - ((i)*((i)+1))/2 + (j))

__device__ __forceinline__ float tfast(float x){
  // weights pre-scaled by 2*log2e: tanh(pre) = 1 - 2/(exp2(x)+1)
  float e = FEXP2(x);
  return 1.f - 2.f * FRCP(e + 1.f);
}

__global__ void prep_kernel(const float* __restrict__ Wh, const float* __restrict__ bh,
                            const float* __restrict__ Wx, const float* __restrict__ bx,
                            const float* __restrict__ Wo, const float* __restrict__ bo,
                            const float* __restrict__ Wf, float* __restrict__ ws){
  int t = threadIdx.x;                       // 1 block x 256
  for (int i=t;i<128;i+=256) ws[i]=0.f;      // zero norm accumulators
  for (int i=t;i<800;i+=256){
    int h=i>>4, d=i&15;
    ws[WS_WHP+i] = (d<D)? Wh[h*D+d]*TSC : 0.f;
  }
  for (int i=t;i<64;i+=256) ws[WS_BHX+i] = (i<H)? (bh[i]+bx[i])*TSC : 0.f;
  for (int i=t;i<16;i+=256) ws[WS_BO+i]  = (i<D)? bo[i]*TSC : 0.f;
  __half2* wx2 = (__half2*)(ws + WS_WX2);
  for (int i=t;i<400;i+=256){
    int h=i>>3, dd=i&7, d0=2*dd, d1=2*dd+1;
    float a=(d0<D)?Wx[h*D+d0]*TSC:0.f, b=(d1<D)?Wx[h*D+d1]*TSC:0.f;
    wx2[i] = __floats2half2_rn(a,b);
  }
  __half2* wo2 = (__half2*)(ws + WS_WO2);
  for (int i=t;i<364;i+=256){
    int d=i/26, hh=i-26*d, h0=2*hh, h1=2*hh+1;
    float a=(hh<25)?Wo[d*H+h0]*TSC:0.f, b=(hh<25)?Wo[d*H+h1]*TSC:0.f;
    wo2[i] = __floats2half2_rn(a,b);
  }
  __half2* wf2 = (__half2*)(ws + WS_WF2);
  for (int i=t;i<256;i+=256){
    int s=i>>3, dd=i&7, d0=2*dd, d1=2*dd+1;
    float a=(s<S && d0<D)?Wf[s*D+d0]:0.f, b=(s<S && d1<D)?Wf[s*D+d1]:0.f;
    wf2[i] = __floats2half2_rn(a,b);
  }
}

// f-eval, fused layers; weights via wave-uniform addresses (s_load/SGPR path).
#define FEVAL() do{ \
  float oacc_[14]; \
  _Pragma("unroll") for (int d_=0; d_<14; ++d_) oacc_[d_] = bop[d_]; \
  _Pragma("unroll") \
  for (int hh_=0; hh_<25; ++hh_){ \
    f16x2 hx2_ = hxr2[hh_]; \
    float a0_ = (float)hx2_[0], b0_ = (float)hx2_[1]; \
    _Pragma("unroll") for (int q_=0;q_<7;++q_){ \
      a0_ = FDOT2(xvh[q_], wx2[(2*hh_)*8+q_],   a0_); \
      b0_ = FDOT2(xvh[q_], wx2[(2*hh_+1)*8+q_], b0_); } \
    f16x2 th_ = PKRTZ(tfast(a0_), tfast(b0_)); \
    _Pragma("unroll") for (int d_=0; d_<14; ++d_) \
      oacc_[d_] = FDOT2(th_, wo2[d_*26+hh_], oacc_[d_]); \
  } \
  _Pragma("unroll") for (int dp_=0; dp_<7; ++dp_) \
    fvh[dp_] = PKRTZ(tfast(oacc_[2*dp_]), tfast(oacc_[2*dp_+1])); \
}while(0)

#define ZERO_INACT() do{ \
  if (!act){ \
    _Pragma("unroll") for (int q_=0;q_<7;++q_){ fvh[q_]=zzv; gvh[q_]=zzv; } \
  } \
}while(0)

// Shift-based history push (constant indices -> stays in regs).
// All 8 per-iteration 32-lane reductions batched; levels 1/2/4/8 via DPP
// row_ror (pure VALU), only the 16-level crosses rows via ds-shfl.
#define PUSHB(DOPROJ) do{ \
  float rv_[8]; \
  _Pragma("unroll") for (int j_=0;j_<5;++j_){ \
    float acc_=0.f; \
    _Pragma("unroll") for (int q_=0;q_<7;++q_) acc_ = FDOT2(gvh[q_], Gh[(j_+1)*7+q_], acc_); \
    rv_[j_] = acc_; } \
  d2l=0.f; f2l=0.f; \
  _Pragma("unroll") for (int q_=0;q_<7;++q_){ \
    d2l = FDOT2(gvh[q_], gvh[q_], d2l); \
    f2l = FDOT2(fvh[q_], fvh[q_], f2l); } \
  rv_[5]=d2l; rv_[6]=f2l; rv_[7]=0.f; \
  if (DOPROJ){ \
    float pa_=0.f; \
    _Pragma("unroll") for (int q_=0;q_<7;++q_) pa_ = FDOT2(fvh[q_], wfr[q_], pa_); \
    rv_[7]=pa_; } \
  _Pragma("unroll") for (int i_=0;i_<8;++i_) rv_[i_] = dppadd<0x121>(rv_[i_]); \
  _Pragma("unroll") for (int i_=0;i_<8;++i_) rv_[i_] = dppadd<0x122>(rv_[i_]); \
  _Pragma("unroll") for (int i_=0;i_<8;++i_) rv_[i_] = dppadd<0x124>(rv_[i_]); \
  _Pragma("unroll") for (int i_=0;i_<8;++i_) rv_[i_] = dppadd<0x128>(rv_[i_]); \
  _Pragma("unroll") for (int i_=0;i_<8;++i_) rv_[i_] += __shfl_xor(rv_[i_], 16); \
  d2r = rv_[5]; f2r = rv_[6]; po_red = rv_[7]; \
  _Pragma("unroll") for (int j_=0;j_<5;++j_) \
    _Pragma("unroll") for (int q_=0;q_<7;++q_){ \
      Fh[j_*7+q_] = Fh[(j_+1)*7+q_]; Gh[j_*7+q_] = Gh[(j_+1)*7+q_]; } \
  _Pragma("unroll") for (int q_=0;q_<7;++q_){ Fh[35+q_]=fvh[q_]; Gh[35+q_]=gvh[q_]; } \
  _Pragma("unroll") for (int i_=0;i_<5;++i_) \
    _Pragma("unroll") for (int j_=i_;j_<5;++j_) GG[AIJ(i_,j_)] = GG[AIJ(i_+1,j_+1)]; \
  _Pragma("unroll") for (int j_=0;j_<5;++j_) GG[AIJ(j_,5)] = rv_[j_]; \
  GG[AIJ(5,5)] = d2r; \
}while(0)

// One wave per block; no barriers.
__global__ __launch_bounds__(64, 3)
void solver_kernel(const float* __restrict__ x,
                   const float* __restrict__ whp, const float* __restrict__ bhx,
                   const float* __restrict__ bop,
                   const f16x2* __restrict__ wx2, const f16x2* __restrict__ wo2,
                   const f16x2* __restrict__ wf2,
                   float* __restrict__ outk, float* __restrict__ d2p, float* __restrict__ f2p){
  const int tid  = threadIdx.x;
  const int lane = tid & 63;
  const int s    = tid & 31;
  const int elem = blockIdx.x*2 + (tid>>5);
  const bool act = (s < S);

  // hx as f16x2, stride 27 words (odd -> all-bank spread)
  __shared__ f16x2 hx2_sh[64*27];           // 6912 B
  f16x2* hxw2 = hx2_sh + tid*27;

  { // prologue: hx[h] = (x_s . Wh_h + bh_h + bx_h)*TSC (scale via weights)
    float xd[D];
#pragma unroll
    for (int d=0; d<D; ++d) xd[d]=0.f;
    if (act){
      const float* xr = x + ((size_t)elem*S + s)*D;
#pragma unroll
      for (int d=0; d<D; ++d) xd[d]=xr[d];
    }
#pragma unroll 5
    for (int hp=0; hp<25; ++hp){
      float a0 = bhx[2*hp], a1 = bhx[2*hp+1];
#pragma unroll
      for (int d=0; d<D; ++d){
        a0 += xd[d]*whp[(2*hp)*16+d];
        a1 += xd[d]*whp[(2*hp+1)*16+d];
      }
      hxw2[hp] = pack_rn(a0, a1);
    }
  }
  const f16x2* hxr2 = hxw2;
  const f16x2 zzv = {(_Float16)0.f, (_Float16)0.f};
  const f16x2* wfr = wf2 + s*8;

  f16x2 Fh[42], Gh[42], xvh[7], fvh[7], gvh[7];
  float GG[21];
  float d2l, f2l, d2r, f2r, po_red;
#pragma unroll
  for (int i=0;i<42;++i){ Fh[i]=zzv; Gh[i]=zzv; }
#pragma unroll
  for (int i=0;i<21;++i) GG[i]=0.f;

  // init entry 0: X0=0, F0=f(0)
#pragma unroll
  for (int q=0;q<7;++q) xvh[q]=zzv;
  FEVAL();
#pragma unroll
  for (int q=0;q<7;++q) gvh[q]=fvh[q]-xvh[q];
  ZERO_INACT();
  PUSHB(0);
  // init entry 1: X1=F0, F1=f(F0)
#pragma unroll
  for (int q=0;q<7;++q) xvh[q]=fvh[q];
  FEVAL();
#pragma unroll
  for (int q=0;q<7;++q) gvh[q]=fvh[q]-xvh[q];
  ZERO_INACT();
  PUSHB(0);

#pragma unroll 1
  for (int kk=2; kk<50; ++kk){
    float A_[21], invd[6], yv[6];
    if (kk >= 6){
#pragma unroll
      for (int i=0;i<6;++i)
#pragma unroll
        for (int j=i;j<6;++j) A_[AIJ(i,j)] = GG[AIJ(i,j)] + ((i==j)?LAMR:0.f);
    } else {
      int lo = 6-kk;
#pragma unroll
      for (int i=0;i<6;++i)
#pragma unroll
        for (int j=i;j<6;++j){
          float v = GG[AIJ(i,j)] + ((i==j)?LAMR:0.f);
          A_[AIJ(i,j)] = (i>=lo)? v : ((i==j)?1e30f:0.f);
        }
    }
#pragma unroll
    for (int i=0;i<6;++i) yv[i]=1.f;
    // symmetric GE (no pivoting; SPD + big-diag pads)
#pragma unroll
    for (int p=0;p<6;++p){
      invd[p] = FRCP(A_[AIJ(p,p)]);
#pragma unroll
      for (int i=p+1;i<6;++i){
        float m = A_[AIJ(p,i)]*invd[p];
#pragma unroll
        for (int j=i;j<6;++j) A_[AIJ(i,j)] -= m*A_[AIJ(p,j)];
        yv[i] -= m*yv[p];
      }
    }
#pragma unroll
    for (int p=5;p>=0;--p){
      float acc=yv[p];
#pragma unroll
      for (int j=p+1;j<6;++j) acc -= A_[AIJ(p,j)]*yv[j];
      yv[p]=acc*invd[p];
    }
    float isum = FRCP(yv[0]+yv[1]+yv[2]+yv[3]+yv[4]+yv[5]);
    // Xk = sum_j alpha_j F_j  (fp16 packed)
#pragma unroll
    for (int q=0;q<7;++q) xvh[q]=zzv;
#pragma unroll
    for (int j=0;j<6;++j){
      _Float16 ah = (_Float16)(yv[j]*isum);
      f16x2 a2 = {ah, ah};
#pragma unroll
      for (int q=0;q<7;++q) xvh[q] += a2*Fh[j*7+q];
    }
    FEVAL();
#pragma unroll
    for (int q=0;q<7;++q) gvh[q]=fvh[q]-xvh[q];
    ZERO_INACT();
    PUSHB(1);
    float d2w = d2r + __shfl_xor(d2r, 32);
    float f2w = f2r + __shfl_xor(f2r, 32);
    if (lane==0){ atomicAdd(&d2p[kk-2], d2w); atomicAdd(&f2p[kk-2], f2w); }
    if (s==0) outk[(size_t)(kk-2)*NB + elem] = po_red;
  }
}

__global__ void final_kernel(const float* __restrict__ d2p, const float* __restrict__ f2p,
                             const float* __restrict__ outk, const float* __restrict__ bf,
                             float* __restrict__ out){
  int b = blockIdx.x*blockDim.x + threadIdx.x;
  float best = 1e8f; int kst = 0;
  for (int k=0;k<NITER;++k){
    float rel = sqrtf(d2p[k]) / (1e-5f + sqrtf(f2p[k]));
    if (rel < best){ best = rel; kst = k; }
  }
  out[b] = outk[(size_t)kst*NB + b] + bf[0];
}

extern "C" void kernel_launch(void* const* d_in, const int* in_sizes, int n_in,
                              void* d_out, int out_size, void* d_ws, size_t ws_size,
                              hipStream_t stream){
  const float* x  = (const float*)d_in[0];
  const float* Wh = (const float*)d_in[1];
  const float* bh = (const float*)d_in[2];
  const float* Wx = (const float*)d_in[3];
  const float* bx = (const float*)d_in[4];
  const float* Wo = (const float*)d_in[5];
  const float* bo = (const float*)d_in[6];
  const float* Wf = (const float*)d_in[7];
  const float* bf = (const float*)d_in[8];
  float* ws  = (float*)d_ws;
  float* out = (float*)d_out;

  hipLaunchKernelGGL(prep_kernel, dim3(1), dim3(256), 0, stream, Wh,bh,Wx,bx,Wo,bo,Wf,ws);
  hipLaunchKernelGGL(solver_kernel, dim3(NB/2), dim3(64), 0, stream,
                     x, ws+WS_WHP, ws+WS_BHX, ws+WS_BO,
                     (const f16x2*)(ws+WS_WX2), (const f16x2*)(ws+WS_WO2), (const f16x2*)(ws+WS_WF2),
                     ws+WS_OUTK, ws+WS_D2, ws+WS_F2);
  hipLaunchKernelGGL(final_kernel, dim3(NB/256), dim3(256), 0, stream,
                     ws+WS_D2, ws+WS_F2, ws+WS_OUTK, bf, out);
}